// Round 5
// baseline (4941.347 us; speedup 1.0000x reference)
//
#include <hip/hip_runtime.h>
#include <stdint.h>

// LSTM: T=1024, B=32, I=512, H=512, fp32. Persistent-style, plain launch.
// R9 (post-mortem R8: 4 waves/SIMD regressed 3742->4829; VGPR 128->64 cut
// per-wave ILP and 16-wave barriers/narrow phases grew the serial fraction.
// Knee is 2 waves/SIMD -> revert to R7 shape, attack the serial skeleton):
//  - barriers 4 -> 2 per step (D, E only):
//    * barrier F + garr eliminated: reduce threads (tid<256, lr=tid&31,
//      b=tid>>5) hold all 4 gate rows of a cell in one wave; 3 __shfl's
//      replace garr write/barrier/read; activation+publish inline.
//    * barrier A eliminated: xtile double-buffered; x[t+1] global-loads
//      issue at loop top (hidden under x-proj), ds_write to the other
//      buffer pre-validate. All cross-step LDS hazards ordered by D/E.
//  - early-revalidate pass between x-proj and x-stage: stale first-look
//    words reload with the staging writes as cover.
//  - waves 4-7 skip P8 and run ahead into t+1 x-prefetch/x-proj while
//    waves 0-3 reduce/publish step t.
// Ring protocol unchanged from R4: fused ((fp32_bits<<32)|tag) words, depth 4,
// relaxed agent-scope atomics, poison 0xAAAAAAAA != any tag (1..1024).
//
// 256 blocks = 4 batch-groups (bg) x 64 j-groups (jg). Weights in VGPRs for
// all 1024 steps. c-state block-local. out[] gets plain fp32 stores only.

#define T_STEPS 1024
#define BATCH   32
#define IDIM    512
#define HDIM    512

#define BG      4
#define JG      64
#define NBLK    (BG*JG)
#define BPB     (BATCH/BG)   // 8 batches/block
#define JPB     (HDIM/JG)    // 8 hidden units/block
#define RPB     (4*JPB)      // 32 gate rows/block
#define NTHR    512          // 8 waves -> 2 waves/SIMD (R7-proven knee)
#define PSTRIDE 257          // odd stride -> worst 2-way (free) LDS conflicts
#define RING_D  4
#define HWORDS  (BPB*HDIM)   // 4096 tagged words per (slot,bg)
#define WPT     (HWORDS/NTHR) // 8 words per consumer thread

__device__ __forceinline__ float sigmoid_f(float v) {
    return 1.0f / (1.0f + __expf(-v));
}
__device__ __forceinline__ float tanh_f(float v) {
    float e = __expf(2.0f * v);
    return 1.0f - 2.0f / (e + 1.0f);
}

__global__ __launch_bounds__(NTHR, 1) void lstm_persistent(
    const float* __restrict__ x,     // [T][B][I]
    const float* __restrict__ h0,    // [B][H]
    const float* __restrict__ c0,    // [B][H]
    const float* __restrict__ Wih,   // [4H][I]
    const float* __restrict__ Whh,   // [4H][H]
    const float* __restrict__ bih,   // [4H]
    const float* __restrict__ bhh,   // [4H]
    float* __restrict__ out,         // [T][B][H] ++ h_f[B][H] ++ c_f[B][H]
    unsigned long long* __restrict__ ring)  // [4][BG][HWORDS] tagged words
{
    __shared__ __align__(16) float xtile[2][BPB * IDIM]; // 32 KB (dbuf)
    __shared__ __align__(16) float htile[BPB * HDIM];    // 16 KB
    __shared__ float part[RPB * PSTRIDE];                // 32.9 KB
    __shared__ float biasl[RPB];

    const int tid = threadIdx.x;
    const int bid = blockIdx.x;
    const int bg  = bid >> 6;        // 0..3
    const int jg  = bid & 63;        // 0..63
    const int ks  = tid >> 4;        // 0..31 k-slice
    const int rp  = tid & 15;        // 0..15 row-pair

    // ---- weight slices -> registers (held for all steps) ----
    float4 wih[2][4], whh[2][4];
    #pragma unroll
    for (int r = 0; r < 2; ++r) {
        const int lr = rp * 2 + r;                                // 0..31
        const int grow = (lr >> 3) * HDIM + jg * JPB + (lr & 7);  // gate*512+j
        const float* wi = Wih + (size_t)grow * IDIM;
        const float* wh = Whh + (size_t)grow * HDIM;
        #pragma unroll
        for (int j = 0; j < 4; ++j) {
            const int k = ks * 4 + j * 128;
            wih[r][j] = *(const float4*)(wi + k);
            whh[r][j] = *(const float4*)(wh + k);
        }
    }
    if (tid < RPB) {
        const int grow = (tid >> 3) * HDIM + jg * JPB + (tid & 7);
        biasl[tid] = bih[grow] + bhh[grow];
    }

    // reduce/activation mapping (tid<256): row lr_red, batch b_red.
    // A wave holds all 4 gate rows of each cell -> gate gather via shfl.
    const int lr_red = tid & 31;     // gate row 0..31
    const int b_red  = tid >> 5;     // batch 0..7 (valid tid<256)
    const int lid    = tid & 63;     // lane in wave
    const bool is_act = (tid < 256) && (lr_red < 8);  // 64 activation lanes
    float cst = 0.f, hl = 0.f;
    if (is_act) {
        cst = c0[(size_t)(bg * BPB + b_red) * HDIM + jg * JPB + lr_red];
    }

    // ---- prologue: stage x[0] -> xtile[0], h0 -> htile ----
    {
        const float* xsrc = x + (size_t)(bg * BPB) * IDIM;
        const float* hsrc = h0 + (size_t)bg * BPB * HDIM;
        #pragma unroll
        for (int i = 0; i < 2; ++i) {
            const int f = i * 2048 + tid * 4;
            *(float4*)(&xtile[0][f]) = *(const float4*)(xsrc + f);
            *(float4*)(htile + f)    = *(const float4*)(hsrc + f);
        }
    }
    __syncthreads();

    for (int t = 0; t < T_STEPS; ++t) {
        // ---- P1: ring first-look + x[t+1] global issue (both hidden) ----
        unsigned long long v[WPT];
        const unsigned int tag = (unsigned int)t;   // producers wrote (t-1)+1
        const unsigned long long* rb =
            ring + ((size_t)((t - 1) & 3) * BG + bg) * HWORDS;
        if (t > 0) {
            #pragma unroll
            for (int w = 0; w < WPT; ++w)
                v[w] = __hip_atomic_load(rb + w * NTHR + tid,
                                         __ATOMIC_RELAXED,
                                         __HIP_MEMORY_SCOPE_AGENT);
        }
        float4 xr0, xr1;
        if (t + 1 < T_STEPS) {
            const float* xsrc = x + ((size_t)(t + 1) * BATCH + bg * BPB) * IDIM;
            xr0 = *(const float4*)(xsrc + tid * 4);
            xr1 = *(const float4*)(xsrc + 2048 + tid * 4);
        }

        // ---- P2: x projection from xtile[t&1] ----
        const float* xt = xtile[t & 1];
        float acc[2][BPB];
        #pragma unroll
        for (int r = 0; r < 2; ++r)
            #pragma unroll
            for (int b = 0; b < BPB; ++b) acc[r][b] = 0.0f;

        #pragma unroll
        for (int j = 0; j < 4; ++j) {
            #pragma unroll
            for (int b = 0; b < BPB; ++b) {
                const float4 vx = *(const float4*)(xt + b * IDIM + ks * 4 + j * 128);
                #pragma unroll
                for (int r = 0; r < 2; ++r) {
                    acc[r][b] = fmaf(wih[r][j].x, vx.x, acc[r][b]);
                    acc[r][b] = fmaf(wih[r][j].y, vx.y, acc[r][b]);
                    acc[r][b] = fmaf(wih[r][j].z, vx.z, acc[r][b]);
                    acc[r][b] = fmaf(wih[r][j].w, vx.w, acc[r][b]);
                }
            }
        }

        // ---- P3: early revalidate (reload RT hides under x-staging) ----
        if (t > 0) {
            #pragma unroll
            for (int w = 0; w < WPT; ++w)
                if ((unsigned int)v[w] != tag)
                    v[w] = __hip_atomic_load(rb + w * NTHR + tid,
                                             __ATOMIC_RELAXED,
                                             __HIP_MEMORY_SCOPE_AGENT);
        }

        // ---- P4: stage x[t+1] into the other xtile buffer ----
        if (t + 1 < T_STEPS) {
            float* xd = xtile[(t + 1) & 1];
            *(float4*)(xd + tid * 4)        = xr0;
            *(float4*)(xd + 2048 + tid * 4) = xr1;
        }

        // ---- P5: final validate sweep; write h into htile ----
        if (t > 0) {
            for (int sweep = 0; sweep < 30000; ++sweep) {
                bool ok = true;
                #pragma unroll
                for (int w = 0; w < WPT; ++w) {
                    if ((unsigned int)v[w] != tag) {
                        v[w] = __hip_atomic_load(rb + w * NTHR + tid,
                                                 __ATOMIC_RELAXED,
                                                 __HIP_MEMORY_SCOPE_AGENT);
                        ok = false;
                    }
                }
                if (ok) break;                     // bail path -> visible error
                __builtin_amdgcn_s_sleep(1);
            }
            #pragma unroll
            for (int w = 0; w < WPT; ++w)
                htile[w * NTHR + tid] =
                    __uint_as_float((unsigned int)(v[w] >> 32));
        }
        __syncthreads();   // D: htile + next xtile ready; part reuse ordered

        // ---- P6: h projection ----
        #pragma unroll
        for (int j = 0; j < 4; ++j) {
            #pragma unroll
            for (int b = 0; b < BPB; ++b) {
                const float4 vh = *(const float4*)(htile + b * HDIM + ks * 4 + j * 128);
                #pragma unroll
                for (int r = 0; r < 2; ++r) {
                    acc[r][b] = fmaf(whh[r][j].x, vh.x, acc[r][b]);
                    acc[r][b] = fmaf(whh[r][j].y, vh.y, acc[r][b]);
                    acc[r][b] = fmaf(whh[r][j].z, vh.z, acc[r][b]);
                    acc[r][b] = fmaf(whh[r][j].w, vh.w, acc[r][b]);
                }
            }
        }

        // ---- P7: spill partials ----
        #pragma unroll
        for (int r = 0; r < 2; ++r) {
            const int lr = rp * 2 + r;
            #pragma unroll
            for (int b = 0; b < BPB; ++b)
                part[lr * PSTRIDE + b * 32 + ks] = acc[r][b];
        }
        __syncthreads();   // E

        // ---- P8: reduce + in-wave gate gather + activation + publish ----
        // waves 4-7 skip ahead into t+1's P1/P2 (overlaps this tail).
        if (tid < 256) {
            const float* p = part + lr_red * PSTRIDE + b_red * 32;
            float s0 = 0.f, s1 = 0.f, s2 = 0.f, s3 = 0.f;
            #pragma unroll
            for (int k2 = 0; k2 < 32; k2 += 4) {
                s0 += p[k2]; s1 += p[k2 + 1]; s2 += p[k2 + 2]; s3 += p[k2 + 3];
            }
            const float s = (s0 + s1) + (s2 + s3) + biasl[lr_red];

            // gate rows of cell j sit at lanes hb+j, +8, +16, +24 (hb=lid&32)
            const int hb = lid & 32;
            const float fs = __shfl(s, hb | ((lid + 8)  & 31), 64);
            const float gs = __shfl(s, hb | ((lid + 16) & 31), 64);
            const float os = __shfl(s, hb | ((lid + 24) & 31), 64);

            if (lr_red < 8) {   // 16 activation lanes per wave
                const float ig = sigmoid_f(s);
                const float fg = sigmoid_f(fs);
                const float gg = tanh_f(gs);
                const float og = sigmoid_f(os);
                cst = fmaf(fg, cst, ig * gg);
                hl  = og * tanh_f(cst);

                // tagged ring publish FIRST (earliest visibility on chain)
                unsigned long long* rw = ring
                    + ((size_t)(t & 3) * BG + bg) * HWORDS
                    + b_red * HDIM + jg * JPB + lr_red;
                __hip_atomic_store(rw,
                    (((unsigned long long)__float_as_uint(hl)) << 32)
                        | (unsigned long long)(t + 1),
                    __ATOMIC_RELAXED, __HIP_MEMORY_SCOPE_AGENT);

                // output store (plain; nobody reads out[] during the run)
                out[((size_t)t * BATCH + bg * BPB + b_red) * HDIM
                    + jg * JPB + lr_red] = hl;
            }
        }
        // no barrier: next step's P1-P5 touch no LDS written before D/E
    }

    // ---- final states h_f, c_f ----
    if (is_act) {
        const size_t base = (size_t)T_STEPS * BATCH * HDIM;
        const size_t off  = (size_t)(bg * BPB + b_red) * HDIM + jg * JPB + lr_red;
        out[base + off] = hl;
        out[base + (size_t)BATCH * HDIM + off] = cst;
    }
}

extern "C" void kernel_launch(void* const* d_in, const int* in_sizes, int n_in,
                              void* d_out, int out_size, void* d_ws, size_t ws_size,
                              hipStream_t stream) {
    const float* x   = (const float*)d_in[0];
    const float* h0  = (const float*)d_in[1];
    const float* c0  = (const float*)d_in[2];
    const float* Wih = (const float*)d_in[3];
    const float* Whh = (const float*)d_in[4];
    const float* bih = (const float*)d_in[5];
    const float* bhh = (const float*)d_in[6];
    float* out = (float*)d_out;
    unsigned long long* ring = (unsigned long long*)d_ws;  // 512 KB; 0xAA poison
                                                           // != any tag -> no init
    lstm_persistent<<<dim3(NBLK), dim3(NTHR), 0, stream>>>(
        x, h0, c0, Wih, Whh, bih, bhh, out, ring);
}

// Round 6
// 4902.411 us; speedup vs baseline: 1.0079x; 1.0079x over previous
//
#include <hip/hip_runtime.h>
#include <stdint.h>

// LSTM: T=1024, B=32, I=512, H=512, fp32. Persistent-style, plain launch.
// R10 (post-mortem R9: +32% regression, FETCH +195MB = extra ring-poll
// traffic. TWICE-confirmed rule (R6, R9): ring first-look must issue at
// R7's timing -- after x-stage + barrier A -- not earlier; early looks are
// staler and each stale word costs an exposed ~700cy reload RT).
// R10 = exact R7 structure (proven 3742 us: 512 thr, barriers A/D/E, R7
// ring timing) + ONE cut: barrier F + garr eliminated via in-wave shfl.
// Reduce threads (tid<256, lr=tid&31, b=tid>>5) hold all 4 gate rows of a
// cell in one wave; 3 __shfl's gather f/g/o partial sums; activation +
// ring publish + out store run inline. Waves 4-7 skip straight to x[t+1]
// staging. Hazard audit: part[] reads (post-E) vs next writes (post-A+D)
// ordered; xtile staging vs step-t reads ordered by D,E; htile P5 write
// (t+1, post-A) vs P6 read (t, pre-E) ordered by E,A.
// Ring protocol unchanged from R4: fused ((fp32_bits<<32)|tag) words, depth 4,
// relaxed agent-scope atomics, poison 0xAAAAAAAA != any tag (1..1024).
//
// 256 blocks = 4 batch-groups (bg) x 64 j-groups (jg). Weights in VGPRs for
// all 1024 steps. c-state block-local. out[] gets plain fp32 stores only.

#define T_STEPS 1024
#define BATCH   32
#define IDIM    512
#define HDIM    512

#define BG      4
#define JG      64
#define NBLK    (BG*JG)
#define BPB     (BATCH/BG)   // 8 batches/block
#define JPB     (HDIM/JG)    // 8 hidden units/block
#define RPB     (4*JPB)      // 32 gate rows/block
#define NTHR    512          // 8 waves -> 2 waves/SIMD (R7-proven knee)
#define PSTRIDE 257          // odd stride -> worst 2-way (free) LDS conflicts
#define RING_D  4
#define HWORDS  (BPB*HDIM)   // 4096 tagged words per (slot,bg)
#define WPT     (HWORDS/NTHR) // 8 words per consumer thread

__device__ __forceinline__ float sigmoid_f(float v) {
    return 1.0f / (1.0f + __expf(-v));
}
__device__ __forceinline__ float tanh_f(float v) {
    float e = __expf(2.0f * v);
    return 1.0f - 2.0f / (e + 1.0f);
}

__global__ __launch_bounds__(NTHR, 1) void lstm_persistent(
    const float* __restrict__ x,     // [T][B][I]
    const float* __restrict__ h0,    // [B][H]
    const float* __restrict__ c0,    // [B][H]
    const float* __restrict__ Wih,   // [4H][I]
    const float* __restrict__ Whh,   // [4H][H]
    const float* __restrict__ bih,   // [4H]
    const float* __restrict__ bhh,   // [4H]
    float* __restrict__ out,         // [T][B][H] ++ h_f[B][H] ++ c_f[B][H]
    unsigned long long* __restrict__ ring)  // [4][BG][HWORDS] tagged words
{
    __shared__ __align__(16) float xtile[BPB * IDIM];   // 16 KB
    __shared__ __align__(16) float htile[BPB * HDIM];   // 16 KB
    __shared__ float part[RPB * PSTRIDE];               // 32.9 KB
    __shared__ float biasl[RPB];

    const int tid = threadIdx.x;
    const int bid = blockIdx.x;
    const int bg  = bid >> 6;        // 0..3
    const int jg  = bid & 63;        // 0..63
    const int ks  = tid >> 4;        // 0..31 k-slice
    const int rp  = tid & 15;        // 0..15 row-pair

    // ---- weight slices -> registers (held for all steps) ----
    float4 wih[2][4], whh[2][4];
    #pragma unroll
    for (int r = 0; r < 2; ++r) {
        const int lr = rp * 2 + r;                                // 0..31
        const int grow = (lr >> 3) * HDIM + jg * JPB + (lr & 7);  // gate*512+j
        const float* wi = Wih + (size_t)grow * IDIM;
        const float* wh = Whh + (size_t)grow * HDIM;
        #pragma unroll
        for (int j = 0; j < 4; ++j) {
            const int k = ks * 4 + j * 128;
            wih[r][j] = *(const float4*)(wi + k);
            whh[r][j] = *(const float4*)(wh + k);
        }
    }
    if (tid < RPB) {
        const int grow = (tid >> 3) * HDIM + jg * JPB + (tid & 7);
        biasl[tid] = bih[grow] + bhh[grow];
    }

    // reduce/activation mapping (tid<256): row lr_red, batch b_red.
    // Each wave holds all 4 gate rows of its cells -> gate gather via shfl.
    const int lr_red = tid & 31;     // gate row 0..31
    const int b_red  = tid >> 5;     // batch 0..7 (valid tid<256)
    const int lid    = tid & 63;     // lane in wave
    const bool is_act = (tid < 256) && (lr_red < 8);  // 64 activation lanes
    float cst = 0.f, hl = 0.f;
    if (is_act) {
        cst = c0[(size_t)(bg * BPB + b_red) * HDIM + jg * JPB + lr_red];
    }
    __syncthreads();

    for (int t = 0; t < T_STEPS; ++t) {
        // ---- 1. stage x[t] (contiguous lane mapping, conflict-free) ----
        {
            const float* xsrc = x + ((size_t)t * BATCH + bg * BPB) * IDIM;
            #pragma unroll
            for (int i = 0; i < 2; ++i) {
                const int f = i * 2048 + tid * 4;
                *(float4*)(xtile + f) = *(const float4*)(xsrc + f);
            }
        }
        __syncthreads();   // A: xtile ready; also orders part reuse

        // ---- 2. prefetch tagged h(t-1) words (RT hides under x-proj) ----
        // R7-proven timing: AFTER x-stage + barrier A. Do not move earlier.
        unsigned long long v[WPT];
        const unsigned int tag = (unsigned int)t;   // producers wrote (t-1)+1
        const unsigned long long* rb =
            ring + ((size_t)((t - 1) & 3) * BG + bg) * HWORDS;
        if (t > 0) {
            #pragma unroll
            for (int w = 0; w < WPT; ++w)
                v[w] = __hip_atomic_load(rb + w * NTHR + tid,
                                         __ATOMIC_RELAXED,
                                         __HIP_MEMORY_SCOPE_AGENT);
        }

        // ---- 3. x projection ----
        float acc[2][BPB];
        #pragma unroll
        for (int r = 0; r < 2; ++r)
            #pragma unroll
            for (int b = 0; b < BPB; ++b) acc[r][b] = 0.0f;

        #pragma unroll
        for (int j = 0; j < 4; ++j) {
            #pragma unroll
            for (int b = 0; b < BPB; ++b) {
                const float4 vx = *(const float4*)(xtile + b * IDIM + ks * 4 + j * 128);
                #pragma unroll
                for (int r = 0; r < 2; ++r) {
                    acc[r][b] = fmaf(wih[r][j].x, vx.x, acc[r][b]);
                    acc[r][b] = fmaf(wih[r][j].y, vx.y, acc[r][b]);
                    acc[r][b] = fmaf(wih[r][j].z, vx.z, acc[r][b]);
                    acc[r][b] = fmaf(wih[r][j].w, vx.w, acc[r][b]);
                }
            }
        }

        // ---- 4. validate tags; reload stragglers; write h into htile ----
        if (t > 0) {
            for (int sweep = 0; sweep < 30000; ++sweep) {
                bool ok = true;
                #pragma unroll
                for (int w = 0; w < WPT; ++w) {
                    if ((unsigned int)v[w] != tag) {
                        v[w] = __hip_atomic_load(rb + w * NTHR + tid,
                                                 __ATOMIC_RELAXED,
                                                 __HIP_MEMORY_SCOPE_AGENT);
                        ok = false;
                    }
                }
                if (ok) break;                     // bail path -> visible error
                __builtin_amdgcn_s_sleep(1);
            }
            #pragma unroll
            for (int w = 0; w < WPT; ++w)
                htile[w * NTHR + tid] =
                    __uint_as_float((unsigned int)(v[w] >> 32));
        } else {
            const float* hsrc = h0 + (size_t)bg * BPB * HDIM;
            #pragma unroll
            for (int i = 0; i < 2; ++i) {
                const int f = i * 2048 + tid * 4;
                *(float4*)(htile + f) = *(const float4*)(hsrc + f);
            }
        }
        __syncthreads();   // D: htile ready

        // ---- 5. h projection ----
        #pragma unroll
        for (int j = 0; j < 4; ++j) {
            #pragma unroll
            for (int b = 0; b < BPB; ++b) {
                const float4 vh = *(const float4*)(htile + b * HDIM + ks * 4 + j * 128);
                #pragma unroll
                for (int r = 0; r < 2; ++r) {
                    acc[r][b] = fmaf(whh[r][j].x, vh.x, acc[r][b]);
                    acc[r][b] = fmaf(whh[r][j].y, vh.y, acc[r][b]);
                    acc[r][b] = fmaf(whh[r][j].z, vh.z, acc[r][b]);
                    acc[r][b] = fmaf(whh[r][j].w, vh.w, acc[r][b]);
                }
            }
        }

        // ---- 6. spill partials ----
        #pragma unroll
        for (int r = 0; r < 2; ++r) {
            const int lr = rp * 2 + r;
            #pragma unroll
            for (int b = 0; b < BPB; ++b)
                part[lr * PSTRIDE + b * 32 + ks] = acc[r][b];
        }
        __syncthreads();   // E

        // ---- 7. reduce + in-wave gate gather + activation + publish ----
        // (barrier F + garr eliminated; waves 4-7 go straight to staging)
        if (tid < 256) {
            const float* p = part + lr_red * PSTRIDE + b_red * 32;
            float s0 = 0.f, s1 = 0.f, s2 = 0.f, s3 = 0.f;
            #pragma unroll
            for (int k2 = 0; k2 < 32; k2 += 4) {
                s0 += p[k2]; s1 += p[k2 + 1]; s2 += p[k2 + 2]; s3 += p[k2 + 3];
            }
            const float s = (s0 + s1) + (s2 + s3) + biasl[lr_red];

            // gate rows of cell j sit at lanes hb+j, +8, +16, +24 (hb=lid&32)
            const int hb = lid & 32;
            const float fs = __shfl(s, hb | ((lid + 8)  & 31), 64);
            const float gs = __shfl(s, hb | ((lid + 16) & 31), 64);
            const float os = __shfl(s, hb | ((lid + 24) & 31), 64);

            if (lr_red < 8) {   // 16 activation lanes per wave
                const float ig = sigmoid_f(s);
                const float fg = sigmoid_f(fs);
                const float gg = tanh_f(gs);
                const float og = sigmoid_f(os);
                cst = fmaf(fg, cst, ig * gg);
                hl  = og * tanh_f(cst);

                // tagged ring publish FIRST (earliest visibility on chain)
                unsigned long long* rw = ring
                    + ((size_t)(t & 3) * BG + bg) * HWORDS
                    + b_red * HDIM + jg * JPB + lr_red;
                __hip_atomic_store(rw,
                    (((unsigned long long)__float_as_uint(hl)) << 32)
                        | (unsigned long long)(t + 1),
                    __ATOMIC_RELAXED, __HIP_MEMORY_SCOPE_AGENT);

                // output store (plain; nobody reads out[] during the run)
                out[((size_t)t * BATCH + bg * BPB + b_red) * HDIM
                    + jg * JPB + lr_red] = hl;
            }
        }
        // no barrier here: next step's staging/A/D order all LDS hazards
    }

    // ---- final states h_f, c_f ----
    if (is_act) {
        const size_t base = (size_t)T_STEPS * BATCH * HDIM;
        const size_t off  = (size_t)(bg * BPB + b_red) * HDIM + jg * JPB + lr_red;
        out[base + off] = hl;
        out[base + (size_t)BATCH * HDIM + off] = cst;
    }
}

extern "C" void kernel_launch(void* const* d_in, const int* in_sizes, int n_in,
                              void* d_out, int out_size, void* d_ws, size_t ws_size,
                              hipStream_t stream) {
    const float* x   = (const float*)d_in[0];
    const float* h0  = (const float*)d_in[1];
    const float* c0  = (const float*)d_in[2];
    const float* Wih = (const float*)d_in[3];
    const float* Whh = (const float*)d_in[4];
    const float* bih = (const float*)d_in[5];
    const float* bhh = (const float*)d_in[6];
    float* out = (float*)d_out;
    unsigned long long* ring = (unsigned long long*)d_ws;  // 512 KB; 0xAA poison
                                                           // != any tag -> no init
    lstm_persistent<<<dim3(NBLK), dim3(NTHR), 0, stream>>>(
        x, h0, c0, Wih, Whh, bih, bhh, out, ring);
}